// Round 1
// baseline (166.496 us; speedup 1.0000x reference)
//
#include <hip/hip_runtime.h>
#include <hip/hip_bf16.h>

typedef __attribute__((ext_vector_type(8))) short short8;
typedef __attribute__((ext_vector_type(4))) float floatx4;

#define DFEAT 128
#define PITCH 136           // bf16 elements per LDS row (+8 pad breaks 256B bank stride)
#define ROWS_PER_BLOCK 64   // 4 waves * 16 rows

__device__ __forceinline__ unsigned short f2bf(float f) {
  unsigned u = __float_as_uint(f);
  u += 0x7FFFu + ((u >> 16) & 1u);   // round-to-nearest-even
  return (unsigned short)(u >> 16);
}

// Fused 2-layer MLP: h2 = relu(relu(x@W1+b1)@W2+b2), output bf16 to workspace.
__global__ __launch_bounds__(256) void mlp2_kernel(
    const float* __restrict__ x, const float* __restrict__ W1,
    const float* __restrict__ b1, const float* __restrict__ W2,
    const float* __restrict__ b2, unsigned short* __restrict__ h2,
    int nNodes) {
  __shared__ unsigned short sW[DFEAT * PITCH];          // W^T bf16: sW[n*PITCH + k]
  __shared__ unsigned short sH[ROWS_PER_BLOCK * PITCH]; // h1 tile:  sH[row*PITCH + n]

  const int tid = threadIdx.x;
  const int wave = tid >> 6;
  const int lane = tid & 63;
  const int quad = lane >> 4;
  const int l16 = lane & 15;
  const int rowbase = blockIdx.x * ROWS_PER_BLOCK + wave * 16;

  // ---- stage W1^T (coalesced global read, transposed LDS write) ----
  #pragma unroll 4
  for (int i = 0; i < 64; ++i) {
    int e = i * 256 + tid;
    int k = e >> 7, n = e & 127;
    sW[n * PITCH + k] = f2bf(W1[e]);
  }
  __syncthreads();

  // ---- layer 1: A = x rows (fp32->bf16 in flight), B = W1^T from LDS ----
  floatx4 acc[8];
  #pragma unroll
  for (int n0 = 0; n0 < 8; ++n0) acc[n0] = (floatx4){0.f, 0.f, 0.f, 0.f};

  const int m = rowbase + l16;
  const bool mvalid = (m < nNodes);

  #pragma unroll
  for (int kk = 0; kk < 4; ++kk) {
    const int kbase = kk * 32 + quad * 8;
    short8 a;
    if (mvalid) {
      const float* xp = x + (size_t)m * DFEAT + kbase;
      float4 f0 = *(const float4*)(xp);
      float4 f1 = *(const float4*)(xp + 4);
      a[0] = (short)f2bf(f0.x); a[1] = (short)f2bf(f0.y);
      a[2] = (short)f2bf(f0.z); a[3] = (short)f2bf(f0.w);
      a[4] = (short)f2bf(f1.x); a[5] = (short)f2bf(f1.y);
      a[6] = (short)f2bf(f1.z); a[7] = (short)f2bf(f1.w);
    } else {
      a = (short8){0,0,0,0,0,0,0,0};
    }
    #pragma unroll
    for (int n0 = 0; n0 < 8; ++n0) {
      short8 b = *(const short8*)&sW[(n0 * 16 + l16) * PITCH + kbase];
      acc[n0] = __builtin_amdgcn_mfma_f32_16x16x32_bf16(a, b, acc[n0], 0, 0, 0);
    }
  }

  // epilogue L1: bias + relu -> bf16 into sH (A-operand layout for layer 2)
  #pragma unroll
  for (int n0 = 0; n0 < 8; ++n0) {
    int col = n0 * 16 + l16;
    float bias = b1[col];
    #pragma unroll
    for (int r = 0; r < 4; ++r) {
      float v = acc[n0][r] + bias;
      v = v > 0.f ? v : 0.f;
      int rl = wave * 16 + quad * 4 + r;   // C/D layout: row = quad*4 + reg
      sH[rl * PITCH + col] = f2bf(v);
    }
  }
  __syncthreads();

  // ---- stage W2^T over W1^T ----
  #pragma unroll 4
  for (int i = 0; i < 64; ++i) {
    int e = i * 256 + tid;
    int k = e >> 7, n = e & 127;
    sW[n * PITCH + k] = f2bf(W2[e]);
  }
  __syncthreads();

  // ---- layer 2: A = h1 tile from LDS, B = W2^T from LDS ----
  #pragma unroll
  for (int n0 = 0; n0 < 8; ++n0) acc[n0] = (floatx4){0.f, 0.f, 0.f, 0.f};

  #pragma unroll
  for (int kk = 0; kk < 4; ++kk) {
    const int kbase = kk * 32 + quad * 8;
    short8 a = *(const short8*)&sH[(wave * 16 + l16) * PITCH + kbase];
    #pragma unroll
    for (int n0 = 0; n0 < 8; ++n0) {
      short8 b = *(const short8*)&sW[(n0 * 16 + l16) * PITCH + kbase];
      acc[n0] = __builtin_amdgcn_mfma_f32_16x16x32_bf16(a, b, acc[n0], 0, 0, 0);
    }
  }

  // epilogue L2: bias + relu -> bf16 to global h2
  #pragma unroll
  for (int n0 = 0; n0 < 8; ++n0) {
    int col = n0 * 16 + l16;
    float bias = b2[col];
    #pragma unroll
    for (int r = 0; r < 4; ++r) {
      float v = acc[n0][r] + bias;
      v = v > 0.f ? v : 0.f;
      int g = rowbase + quad * 4 + r;
      if (g < nNodes) h2[(size_t)g * DFEAT + col] = f2bf(v);
    }
  }
}

__device__ __forceinline__ float dot2bf(unsigned a, unsigned b, float acc) {
  float a0 = __uint_as_float(a << 16);
  float a1 = __uint_as_float(a & 0xFFFF0000u);
  float b0 = __uint_as_float(b << 16);
  float b1 = __uint_as_float(b & 0xFFFF0000u);
  acc = fmaf(a0, b0, acc);
  acc = fmaf(a1, b1, acc);
  return acc;
}

// Edge decode: 16 lanes per edge, each lane reads 16B (8 bf16) of src & dst rows.
__global__ __launch_bounds__(256) void edge_kernel(
    const unsigned short* __restrict__ h2, const int* __restrict__ eidx,
    const int* __restrict__ elabel, float* __restrict__ out, int E) {
  const int sub = threadIdx.x & 15;
  const int e = blockIdx.x * 16 + (threadIdx.x >> 4);
  if (e < E) {
    int s = eidx[e];
    int d = eidx[E + e];
    const uint4 ua = *(const uint4*)(h2 + (size_t)s * DFEAT + sub * 8);
    const uint4 ub = *(const uint4*)(h2 + (size_t)d * DFEAT + sub * 8);
    float acc = 0.f;
    acc = dot2bf(ua.x, ub.x, acc);
    acc = dot2bf(ua.y, ub.y, acc);
    acc = dot2bf(ua.z, ub.z, acc);
    acc = dot2bf(ua.w, ub.w, acc);
    acc += __shfl_xor(acc, 8);
    acc += __shfl_xor(acc, 4);
    acc += __shfl_xor(acc, 2);
    acc += __shfl_xor(acc, 1);
    if (sub == 0) out[e] = acc;
  }
  // labels: int -> float, second half of d_out
  if (threadIdx.x < 16) {
    int le = blockIdx.x * 16 + threadIdx.x;
    if (le < E) out[E + le] = (float)elabel[le];
  }
}

extern "C" void kernel_launch(void* const* d_in, const int* in_sizes, int n_in,
                              void* d_out, int out_size, void* d_ws, size_t ws_size,
                              hipStream_t stream) {
  const float* x  = (const float*)d_in[0];
  const int* eidx = (const int*)d_in[1];
  const int* elab = (const int*)d_in[2];
  const float* W1 = (const float*)d_in[3];
  const float* b1 = (const float*)d_in[4];
  const float* W2 = (const float*)d_in[5];
  const float* b2 = (const float*)d_in[6];
  float* out = (float*)d_out;

  const int nNodes = in_sizes[0] / DFEAT;   // 100000
  const int E = in_sizes[2];                // 500000

  unsigned short* h2 = (unsigned short*)d_ws;  // nNodes*128 bf16 = 25.6 MB

  const int mlpBlocks = (nNodes + ROWS_PER_BLOCK - 1) / ROWS_PER_BLOCK;
  mlp2_kernel<<<mlpBlocks, 256, 0, stream>>>(x, W1, b1, W2, b2, h2, nNodes);

  const int edgeBlocks = (E + 15) / 16;
  edge_kernel<<<edgeBlocks, 256, 0, stream>>>(h2, eidx, elab, out, E);
}

// Round 2
// 147.596 us; speedup vs baseline: 1.1281x; 1.1281x over previous
//
#include <hip/hip_runtime.h>

typedef __attribute__((ext_vector_type(8))) short short8;
typedef __attribute__((ext_vector_type(4))) short short4v;
typedef __attribute__((ext_vector_type(4))) float floatx4;

#define D 128
#define NWAVES 4
#define GRID_MLP 512

__device__ __forceinline__ unsigned short f2bf(float f) {
  unsigned u = __float_as_uint(f);
  u += 0x7FFFu + ((u >> 16) & 1u);   // RNE
  return (unsigned short)(u >> 16);
}

// W stored transposed+swizzled in LDS: element (n,k) at
//   n*128 + (((k>>3) ^ (n&15)) << 3) + (k&7)
// -> B-frag ds_read_b128 is bank-conflict-free.
__device__ __forceinline__ void stageW(const float* __restrict__ W,
                                       unsigned short* __restrict__ sW, int tid) {
  const int n = tid & 127;
  const int tg = tid >> 7;                 // 0..1
  #pragma unroll
  for (int iter = 0; iter < 16; ++iter) {
    const int k0 = iter * 8 + tg * 4;
    float w0 = W[(k0 + 0) * D + n];
    float w1 = W[(k0 + 1) * D + n];
    float w2 = W[(k0 + 2) * D + n];
    float w3 = W[(k0 + 3) * D + n];
    short4v p;
    p[0] = (short)f2bf(w0); p[1] = (short)f2bf(w1);
    p[2] = (short)f2bf(w2); p[3] = (short)f2bf(w3);
    const int idx = n * D + (((k0 >> 3) ^ (n & 15)) << 3) + (k0 & 7);
    *(short4v*)&sW[idx] = p;
  }
}

// sH (per-wave 16x128, XOR-swizzled): element (row,c) at
//   row*128 + ((((c>>3) ^ row) & 15) << 3) + (c&7)

// ---------------- layer 1: h = relu(x @ W1 + b1), fp32 in, bf16 out -------------
__global__ __launch_bounds__(256) void mlp_layer1(
    const float* __restrict__ x, const float* __restrict__ W1,
    const float* __restrict__ b1, unsigned short* __restrict__ h,
    int nNodes, int ntiles) {
  __shared__ unsigned short sW[D * D];
  __shared__ unsigned short sH[NWAVES][16 * D];
  const int tid = threadIdx.x;
  const int wave = tid >> 6, lane = tid & 63;
  const int quad = lane >> 4, l16 = lane & 15;

  stageW(W1, sW, tid);
  __syncthreads();

  float bias[8];
  #pragma unroll
  for (int n0 = 0; n0 < 8; ++n0) bias[n0] = b1[n0 * 16 + l16];

  unsigned short* mysH = sH[wave];

  for (int t = blockIdx.x * NWAVES + wave; t < ntiles; t += GRID_MLP * NWAVES) {
    const int m = t * 16 + l16;
    const bool mv = (m < nNodes);
    float4 xf[8];
    const float* xp = x + (size_t)m * D + quad * 8;
    #pragma unroll
    for (int kk = 0; kk < 4; ++kk) {
      if (mv) {
        xf[2 * kk]     = *(const float4*)(xp + kk * 32);
        xf[2 * kk + 1] = *(const float4*)(xp + kk * 32 + 4);
      } else {
        xf[2 * kk] = make_float4(0, 0, 0, 0);
        xf[2 * kk + 1] = make_float4(0, 0, 0, 0);
      }
    }
    floatx4 acc[8];
    #pragma unroll
    for (int n0 = 0; n0 < 8; ++n0) acc[n0] = (floatx4){0.f, 0.f, 0.f, 0.f};
    #pragma unroll
    for (int kk = 0; kk < 4; ++kk) {
      const float4 f0 = xf[2 * kk], f1 = xf[2 * kk + 1];
      short8 a;
      a[0] = (short)f2bf(f0.x); a[1] = (short)f2bf(f0.y);
      a[2] = (short)f2bf(f0.z); a[3] = (short)f2bf(f0.w);
      a[4] = (short)f2bf(f1.x); a[5] = (short)f2bf(f1.y);
      a[6] = (short)f2bf(f1.z); a[7] = (short)f2bf(f1.w);
      #pragma unroll
      for (int n0 = 0; n0 < 8; ++n0) {
        short8 b = *(const short8*)&sW[(n0 * 16 + l16) * D + (((kk * 4 + quad) ^ l16) << 3)];
        acc[n0] = __builtin_amdgcn_mfma_f32_16x16x32_bf16(a, b, acc[n0], 0, 0, 0);
      }
    }
    // epilogue: bias+relu -> per-wave swizzled sH (C/D scatter), no barrier needed
    #pragma unroll
    for (int n0 = 0; n0 < 8; ++n0) {
      #pragma unroll
      for (int r = 0; r < 4; ++r) {
        float v = acc[n0][r] + bias[n0];
        v = v > 0.f ? v : 0.f;
        const int row = quad * 4 + r;
        const int g = 2 * n0 + (l16 >> 3);   // c>>3
        mysH[row * D + (((g ^ row) & 15) << 3) + (l16 & 7)] = f2bf(v);
      }
    }
    // repack: coalesced row-major stores (4 rows x 256B per instruction)
    #pragma unroll
    for (int i = 0; i < 4; ++i) {
      const int row = i * 4 + quad;
      short8 vrow = *(const short8*)&mysH[row * D + (((l16 ^ row) & 15) << 3)];
      const int g = t * 16 + row;
      if (g < nNodes) *(short8*)&h[(size_t)g * D + l16 * 8] = vrow;
    }
  }
}

// ---------------- layer 2 (in-place): h = relu(h @ W2 + b2), bf16 in/out ---------
__global__ __launch_bounds__(256) void mlp_layer2(
    unsigned short* __restrict__ h, const float* __restrict__ W2,
    const float* __restrict__ b2, int nNodes, int ntiles) {
  __shared__ unsigned short sW[D * D];
  __shared__ unsigned short sH[NWAVES][16 * D];
  const int tid = threadIdx.x;
  const int wave = tid >> 6, lane = tid & 63;
  const int quad = lane >> 4, l16 = lane & 15;

  stageW(W2, sW, tid);
  __syncthreads();

  float bias[8];
  #pragma unroll
  for (int n0 = 0; n0 < 8; ++n0) bias[n0] = b2[n0 * 16 + l16];

  unsigned short* mysH = sH[wave];

  for (int t = blockIdx.x * NWAVES + wave; t < ntiles; t += GRID_MLP * NWAVES) {
    const int m = t * 16 + l16;
    const bool mv = (m < nNodes);
    short8 af[4];
    #pragma unroll
    for (int kk = 0; kk < 4; ++kk) {
      if (mv) af[kk] = *(const short8*)&h[(size_t)m * D + kk * 32 + quad * 8];
      else    af[kk] = (short8){0, 0, 0, 0, 0, 0, 0, 0};
    }
    floatx4 acc[8];
    #pragma unroll
    for (int n0 = 0; n0 < 8; ++n0) acc[n0] = (floatx4){0.f, 0.f, 0.f, 0.f};
    #pragma unroll
    for (int kk = 0; kk < 4; ++kk) {
      #pragma unroll
      for (int n0 = 0; n0 < 8; ++n0) {
        short8 b = *(const short8*)&sW[(n0 * 16 + l16) * D + (((kk * 4 + quad) ^ l16) << 3)];
        acc[n0] = __builtin_amdgcn_mfma_f32_16x16x32_bf16(af[kk], b, acc[n0], 0, 0, 0);
      }
    }
    #pragma unroll
    for (int n0 = 0; n0 < 8; ++n0) {
      #pragma unroll
      for (int r = 0; r < 4; ++r) {
        float v = acc[n0][r] + bias[n0];
        v = v > 0.f ? v : 0.f;
        const int row = quad * 4 + r;
        const int g = 2 * n0 + (l16 >> 3);
        mysH[row * D + (((g ^ row) & 15) << 3) + (l16 & 7)] = f2bf(v);
      }
    }
    #pragma unroll
    for (int i = 0; i < 4; ++i) {
      const int row = i * 4 + quad;
      short8 vrow = *(const short8*)&mysH[row * D + (((l16 ^ row) & 15) << 3)];
      const int g = t * 16 + row;
      if (g < nNodes) *(short8*)&h[(size_t)g * D + l16 * 8] = vrow;
    }
  }
}

__device__ __forceinline__ float dot2bf(unsigned a, unsigned b, float acc) {
  float a0 = __uint_as_float(a << 16);
  float a1 = __uint_as_float(a & 0xFFFF0000u);
  float b0 = __uint_as_float(b << 16);
  float b1 = __uint_as_float(b & 0xFFFF0000u);
  acc = fmaf(a0, b0, acc);
  acc = fmaf(a1, b1, acc);
  return acc;
}

// Edge decode: 16 lanes/edge, 4 edges per group -> 8 gathers in flight/thread.
__global__ __launch_bounds__(256) void edge_kernel(
    const unsigned short* __restrict__ h2, const int* __restrict__ eidx,
    const int* __restrict__ elabel, float* __restrict__ out, int E) {
  const int sub = threadIdx.x & 15;
  const int grp = (blockIdx.x * 256 + threadIdx.x) >> 4;
  const int e0 = grp * 4;
  uint4 va[4], vb[4];
  #pragma unroll
  for (int i = 0; i < 4; ++i) {
    const int e = e0 + i;
    if (e < E) {
      const int s = eidx[e];
      const int d = eidx[E + e];
      va[i] = *(const uint4*)(h2 + (size_t)s * D + sub * 8);
      vb[i] = *(const uint4*)(h2 + (size_t)d * D + sub * 8);
    }
  }
  #pragma unroll
  for (int i = 0; i < 4; ++i) {
    const int e = e0 + i;
    if (e < E) {
      float acc = 0.f;
      acc = dot2bf(va[i].x, vb[i].x, acc);
      acc = dot2bf(va[i].y, vb[i].y, acc);
      acc = dot2bf(va[i].z, vb[i].z, acc);
      acc = dot2bf(va[i].w, vb[i].w, acc);
      acc += __shfl_xor(acc, 8);
      acc += __shfl_xor(acc, 4);
      acc += __shfl_xor(acc, 2);
      acc += __shfl_xor(acc, 1);
      if (sub == 0) out[e] = acc;
    }
  }
  // labels int -> float (coalesced, all threads)
  for (int le = blockIdx.x * 256 + threadIdx.x; le < E; le += gridDim.x * 256)
    out[E + le] = (float)elabel[le];
}

extern "C" void kernel_launch(void* const* d_in, const int* in_sizes, int n_in,
                              void* d_out, int out_size, void* d_ws, size_t ws_size,
                              hipStream_t stream) {
  const float* x  = (const float*)d_in[0];
  const int* eidx = (const int*)d_in[1];
  const int* elab = (const int*)d_in[2];
  const float* W1 = (const float*)d_in[3];
  const float* b1 = (const float*)d_in[4];
  const float* W2 = (const float*)d_in[5];
  const float* b2 = (const float*)d_in[6];
  float* out = (float*)d_out;

  const int nNodes = in_sizes[0] / D;   // 100000
  const int E = in_sizes[2];            // 500000
  const int ntiles = (nNodes + 15) / 16;

  unsigned short* h = (unsigned short*)d_ws;  // nNodes*128 bf16 = 25.6 MB

  mlp_layer1<<<GRID_MLP, 256, 0, stream>>>(x, W1, b1, h, nNodes, ntiles);
  mlp_layer2<<<GRID_MLP, 256, 0, stream>>>(h, W2, b2, nNodes, ntiles);

  const int edgeBlocks = (E + 63) / 64;
  edge_kernel<<<edgeBlocks, 256, 0, stream>>>(h, eidx, elab, out, E);
}

// Round 3
// 140.475 us; speedup vs baseline: 1.1852x; 1.0507x over previous
//
#include <hip/hip_runtime.h>

typedef __attribute__((ext_vector_type(8))) short short8;
typedef __attribute__((ext_vector_type(4))) short short4v;
typedef __attribute__((ext_vector_type(4))) float floatx4;

#define D 128
#define NWAVES 4
#define GRID_MLP 512

__device__ __forceinline__ unsigned short f2bf(float f) {
  unsigned u = __float_as_uint(f);
  u += 0x7FFFu + ((u >> 16) & 1u);   // RNE
  return (unsigned short)(u >> 16);
}

// W stored transposed+swizzled in LDS: element (n,k) at
//   n*128 + (((k>>3) ^ (n&15)) << 3) + (k&7)
// -> B-frag ds_read_b128 is conflict-free (8 lanes per 4-bank group, uniform).
__device__ __forceinline__ void stageW(const float* __restrict__ W,
                                       unsigned short* __restrict__ sW, int tid) {
  const int n = tid & 127;
  const int tg = tid >> 7;                 // 0..1
  #pragma unroll
  for (int iter = 0; iter < 16; ++iter) {
    const int k0 = iter * 8 + tg * 4;
    float w0 = W[(k0 + 0) * D + n];
    float w1 = W[(k0 + 1) * D + n];
    float w2 = W[(k0 + 2) * D + n];
    float w3 = W[(k0 + 3) * D + n];
    short4v p;
    p[0] = (short)f2bf(w0); p[1] = (short)f2bf(w1);
    p[2] = (short)f2bf(w2); p[3] = (short)f2bf(w3);
    const int idx = n * D + (((k0 >> 3) ^ (n & 15)) << 3) + (k0 & 7);
    *(short4v*)&sW[idx] = p;
  }
}

// Fused 2-layer MLP: h2 = relu(relu(x@W1+b1)@W2+b2), fp32 in, bf16 out.
// h1 never touches global: per-wave XOR-swizzled LDS transpose buffer.
// Also writes labels (int->float) into out[E..2E) to overlap with W staging.
__global__ __launch_bounds__(256) void mlp_fused(
    const float* __restrict__ x, const float* __restrict__ W1,
    const float* __restrict__ b1, const float* __restrict__ W2,
    const float* __restrict__ b2, unsigned short* __restrict__ h,
    const int* __restrict__ elabel, float* __restrict__ out,
    int nNodes, int ntiles, int E) {
  __shared__ unsigned short sW1[D * D];          // 32 KB
  __shared__ unsigned short sW2[D * D];          // 32 KB
  __shared__ unsigned short sH[NWAVES][16 * D];  // 16 KB
  const int tid = threadIdx.x;
  const int wave = tid >> 6, lane = tid & 63;
  const int quad = lane >> 4, l16 = lane & 15;

  // labels: coalesced int->float copy, overlapped with staging
  for (int le = blockIdx.x * 256 + tid; le < E; le += GRID_MLP * 256)
    out[E + le] = (float)elabel[le];

  stageW(W1, sW1, tid);
  stageW(W2, sW2, tid);
  __syncthreads();

  float bias1[8], bias2[8];
  #pragma unroll
  for (int n0 = 0; n0 < 8; ++n0) { bias1[n0] = b1[n0 * 16 + l16]; bias2[n0] = b2[n0 * 16 + l16]; }

  unsigned short* mysH = sH[wave];

  for (int t = blockIdx.x * NWAVES + wave; t < ntiles; t += GRID_MLP * NWAVES) {
    const int m = t * 16 + l16;
    const bool mv = (m < nNodes);
    float4 xf[8];
    const float* xp = x + (size_t)m * D + quad * 8;
    #pragma unroll
    for (int kk = 0; kk < 4; ++kk) {
      if (mv) {
        xf[2 * kk]     = *(const float4*)(xp + kk * 32);
        xf[2 * kk + 1] = *(const float4*)(xp + kk * 32 + 4);
      } else {
        xf[2 * kk] = make_float4(0, 0, 0, 0);
        xf[2 * kk + 1] = make_float4(0, 0, 0, 0);
      }
    }
    // ---- layer 1 ----
    floatx4 acc[8];
    #pragma unroll
    for (int n0 = 0; n0 < 8; ++n0) acc[n0] = (floatx4){0.f, 0.f, 0.f, 0.f};
    #pragma unroll
    for (int kk = 0; kk < 4; ++kk) {
      const float4 f0 = xf[2 * kk], f1 = xf[2 * kk + 1];
      short8 a;
      a[0] = (short)f2bf(f0.x); a[1] = (short)f2bf(f0.y);
      a[2] = (short)f2bf(f0.z); a[3] = (short)f2bf(f0.w);
      a[4] = (short)f2bf(f1.x); a[5] = (short)f2bf(f1.y);
      a[6] = (short)f2bf(f1.z); a[7] = (short)f2bf(f1.w);
      #pragma unroll
      for (int n0 = 0; n0 < 8; ++n0) {
        short8 b = *(const short8*)&sW1[(n0 * 16 + l16) * D + (((kk * 4 + quad) ^ l16) << 3)];
        acc[n0] = __builtin_amdgcn_mfma_f32_16x16x32_bf16(a, b, acc[n0], 0, 0, 0);
      }
    }
    // epilogue 1: bias+relu -> per-wave swizzled sH (C/D layout scatter)
    #pragma unroll
    for (int n0 = 0; n0 < 8; ++n0) {
      #pragma unroll
      for (int r = 0; r < 4; ++r) {
        float v = acc[n0][r] + bias1[n0];
        v = v > 0.f ? v : 0.f;
        const int row = quad * 4 + r;
        const int g = 2 * n0 + (l16 >> 3);
        mysH[row * D + (((g ^ row) & 15) << 3) + (l16 & 7)] = f2bf(v);
      }
    }
    // A-fragments of h1 from sH (conflict-free swizzled b128 reads)
    short8 af[4];
    #pragma unroll
    for (int kk = 0; kk < 4; ++kk)
      af[kk] = *(const short8*)&mysH[l16 * D + ((((kk * 4 + quad) ^ l16) & 15) << 3)];
    // ---- layer 2 ----
    #pragma unroll
    for (int n0 = 0; n0 < 8; ++n0) acc[n0] = (floatx4){0.f, 0.f, 0.f, 0.f};
    #pragma unroll
    for (int kk = 0; kk < 4; ++kk) {
      #pragma unroll
      for (int n0 = 0; n0 < 8; ++n0) {
        short8 b = *(const short8*)&sW2[(n0 * 16 + l16) * D + (((kk * 4 + quad) ^ l16) << 3)];
        acc[n0] = __builtin_amdgcn_mfma_f32_16x16x32_bf16(af[kk], b, acc[n0], 0, 0, 0);
      }
    }
    // epilogue 2: bias+relu -> sH (safe overwrite: writes depend on af reads)
    #pragma unroll
    for (int n0 = 0; n0 < 8; ++n0) {
      #pragma unroll
      for (int r = 0; r < 4; ++r) {
        float v = acc[n0][r] + bias2[n0];
        v = v > 0.f ? v : 0.f;
        const int row = quad * 4 + r;
        const int g = 2 * n0 + (l16 >> 3);
        mysH[row * D + (((g ^ row) & 15) << 3) + (l16 & 7)] = f2bf(v);
      }
    }
    // repack: coalesced row-major global stores (4 rows x 256B)
    #pragma unroll
    for (int i = 0; i < 4; ++i) {
      const int row = i * 4 + quad;
      short8 vrow = *(const short8*)&mysH[row * D + (((l16 ^ row) & 15) << 3)];
      const int g = t * 16 + row;
      if (g < nNodes) *(short8*)&h[(size_t)g * D + l16 * 8] = vrow;
    }
  }
}

__device__ __forceinline__ float dot2bf(unsigned a, unsigned b, float acc) {
  float a0 = __uint_as_float(a << 16);
  float a1 = __uint_as_float(a & 0xFFFF0000u);
  float b0 = __uint_as_float(b << 16);
  float b1 = __uint_as_float(b & 0xFFFF0000u);
  acc = fmaf(a0, b0, acc);
  acc = fmaf(a1, b1, acc);
  return acc;
}

__device__ __forceinline__ float edge_dot(const uint4& a, const uint4& b) {
  float acc = 0.f;
  acc = dot2bf(a.x, b.x, acc);
  acc = dot2bf(a.y, b.y, acc);
  acc = dot2bf(a.z, b.z, acc);
  acc = dot2bf(a.w, b.w, acc);
  acc += __shfl_xor(acc, 8);
  acc += __shfl_xor(acc, 4);
  acc += __shfl_xor(acc, 2);
  acc += __shfl_xor(acc, 1);
  return acc;
}

// Edge decode: 16 lanes/edge, 8 edges per group -> 16 gathers (256B) in flight.
__global__ __launch_bounds__(256) void edge_kernel(
    const unsigned short* __restrict__ h2, const int* __restrict__ eidx,
    float* __restrict__ out, int E) {
  const int sub = threadIdx.x & 15;
  const int grp = (blockIdx.x * 256 + threadIdx.x) >> 4;
  const int e0 = grp * 8;
  if (e0 + 8 <= E) {
    const int4 s0 = *(const int4*)&eidx[e0];
    const int4 s1 = *(const int4*)&eidx[e0 + 4];
    const int4 t0 = *(const int4*)&eidx[E + e0];
    const int4 t1 = *(const int4*)&eidx[E + e0 + 4];
    int s[8] = {s0.x, s0.y, s0.z, s0.w, s1.x, s1.y, s1.z, s1.w};
    int d[8] = {t0.x, t0.y, t0.z, t0.w, t1.x, t1.y, t1.z, t1.w};
    uint4 va[8], vb[8];
    #pragma unroll
    for (int i = 0; i < 8; ++i) {
      va[i] = *(const uint4*)(h2 + (size_t)s[i] * D + sub * 8);
      vb[i] = *(const uint4*)(h2 + (size_t)d[i] * D + sub * 8);
    }
    #pragma unroll
    for (int i = 0; i < 8; ++i) {
      float acc = edge_dot(va[i], vb[i]);
      if (sub == 0) out[e0 + i] = acc;
    }
  } else if (e0 < E) {
    for (int e = e0; e < E; ++e) {
      const int s = eidx[e];
      const int d = eidx[E + e];
      const uint4 ua = *(const uint4*)(h2 + (size_t)s * D + sub * 8);
      const uint4 ub = *(const uint4*)(h2 + (size_t)d * D + sub * 8);
      float acc = edge_dot(ua, ub);
      if (sub == 0) out[e] = acc;
    }
  }
}

extern "C" void kernel_launch(void* const* d_in, const int* in_sizes, int n_in,
                              void* d_out, int out_size, void* d_ws, size_t ws_size,
                              hipStream_t stream) {
  const float* x  = (const float*)d_in[0];
  const int* eidx = (const int*)d_in[1];
  const int* elab = (const int*)d_in[2];
  const float* W1 = (const float*)d_in[3];
  const float* b1 = (const float*)d_in[4];
  const float* W2 = (const float*)d_in[5];
  const float* b2 = (const float*)d_in[6];
  float* out = (float*)d_out;

  const int nNodes = in_sizes[0] / D;   // 100000
  const int E = in_sizes[2];            // 500000
  const int ntiles = (nNodes + 15) / 16;

  unsigned short* h = (unsigned short*)d_ws;  // nNodes*128 bf16 = 25.6 MB

  mlp_fused<<<GRID_MLP, 256, 0, stream>>>(x, W1, b1, W2, b2, h, elab, out,
                                          nNodes, ntiles, E);

  const int edgeBlocks = (E + 127) / 128;   // 8 edges per 16-lane group
  edge_kernel<<<edgeBlocks, 256, 0, stream>>>(h, eidx, out, E);
}